// Round 14
// baseline (152.912 us; speedup 1.0000x reference)
//
#include <hip/hip_runtime.h>

#define DI static __device__ __forceinline__

typedef __attribute__((ext_vector_type(8))) short short8;  // 8 bf16 in 4 VGPRs
typedef __attribute__((ext_vector_type(4))) float f32x4;

// fp32 -> bf16 round-to-nearest-even
DI unsigned short f2bf(float f) {
    union { float f; unsigned int u; } v; v.f = f;
    unsigned int r = v.u + 0x7FFFu + ((v.u >> 16) & 1u);
    return (unsigned short)(r >> 16);
}

// pack two fp32 -> u32 of 2 bf16 (RNE)
DI unsigned int f2bf2(float lo, float hi) {
    return (unsigned int)f2bf(lo) | ((unsigned int)f2bf(hi) << 16);
}

// async global->LDS, 16B per lane. LDS dest must be wave-uniform base + lane*16.
DI void gload_lds16(const void* g, void* l) {
    __builtin_amdgcn_global_load_lds(
        (const __attribute__((address_space(1))) void*)g,
        (__attribute__((address_space(3))) void*)l, 16, 0, 0);
}

// swizzled LDS fragment read for 128B-row tiles (attention)
DI short8 ldsfrag(const void* base, int row, int bytecol) {
    return *(const short8*)((const char*)base + row * 128 + (bytecol ^ ((row & 7) << 4)));
}

// ---------------------------------------------------------------------------
// Kernel 1: fp32 -> bf16 conversion, flat 1D grid, 8 elems/thread, 16B store
// ---------------------------------------------------------------------------
__global__ __launch_bounds__(256) void k_cvt(
    const float* __restrict__ x, const float* __restrict__ wq,
    const float* __restrict__ wk, const float* __restrict__ wv,
    const float* __restrict__ wo,
    unsigned short* __restrict__ xb, unsigned short* __restrict__ wqb,
    unsigned short* __restrict__ wkb, unsigned short* __restrict__ wvb,
    unsigned short* __restrict__ wob)
{
    int idx = (blockIdx.x * 256 + threadIdx.x) * 8;   // < 12582912
    const float* src; unsigned short* dst; int off;
    if (idx < 8388608) {
        src = x; dst = xb; off = idx;
    } else {
        int rel = idx - 8388608;
        int sel = rel >> 20;
        off = rel & 1048575;
        switch (sel) {
            case 0:  src = wq; dst = wqb; break;
            case 1:  src = wk; dst = wkb; break;
            case 2:  src = wv; dst = wvb; break;
            default: src = wo; dst = wob; break;
        }
    }
    float4 v0 = *(const float4*)(src + off);
    float4 v1 = *(const float4*)(src + off + 4);
    uint4 o;
    o.x = f2bf2(v0.x, v0.y);
    o.y = f2bf2(v0.z, v0.w);
    o.z = f2bf2(v1.x, v1.y);
    o.w = f2bf2(v1.z, v1.w);
    *(uint4*)(dst + off) = o;
}

// ---------------------------------------------------------------------------
// 128x256 GEMM core (R6/R9/R10-proven, 888 TF, 0 conflicts): BK=32, K=1024,
// 8 waves (2M x 4N), 3 LDS bufs x 24KB = 72KB, counted-vmcnt(3) pipeline.
// ---------------------------------------------------------------------------
DI void gemm_core(const unsigned short* __restrict__ Ag,
                  const unsigned short* __restrict__ Bg,
                  int m0, int n0, char* smem, f32x4 acc[4][4])
{
    const int t = threadIdx.x, lane = t & 63;
    const int wid = t >> 6, wr = wid >> 2, wc = wid & 3;
    const int kl = lane & 15, hi = lane >> 4;

#pragma unroll
    for (int m = 0; m < 4; ++m)
#pragma unroll
        for (int n = 0; n < 4; ++n)
            acc[m][n] = f32x4{0.f, 0.f, 0.f, 0.f};

    const int ca  = t,       ra  = ca  >> 2, sa  = ((ca  & 3) ^ ((ra  >> 1) & 3)) * 8;
    const int cb0 = t,       rb0 = cb0 >> 2, sb0 = ((cb0 & 3) ^ ((rb0 >> 1) & 3)) * 8;
    const int cb1 = t + 512, rb1 = cb1 >> 2, sb1 = ((cb1 & 3) ^ ((rb1 >> 1) & 3)) * 8;
    const unsigned short* pa  = Ag + (long)(m0 + ra)  * 1024 + sa;
    const unsigned short* pb0 = Bg + (long)(n0 + rb0) * 1024 + sb0;
    const unsigned short* pb1 = Bg + (long)(n0 + rb1) * 1024 + sb1;

#define STAGE(TILE, BUF) do {                                          \
        char* _sb = smem + (BUF) * 24576;                              \
        gload_lds16(pa  + (TILE) * 32, _sb + ca * 16);                 \
        gload_lds16(pb0 + (TILE) * 32, _sb + 8192 + cb0 * 16);         \
        gload_lds16(pb1 + (TILE) * 32, _sb + 8192 + cb1 * 16);         \
    } while (0)

    STAGE(0, 0);
    STAGE(1, 1);

    const int swz = ((hi ^ ((kl >> 1) & 3)) << 4);
    const int aoff = (wr * 64 + kl) * 64 + swz;           // + m*1024
    const int boff = 8192 + (wc * 64 + kl) * 64 + swz;    // + n*1024

#define KSTEP(KS, CUR, PRE, ISSUE, VM) do {                                   \
        asm volatile("s_waitcnt vmcnt(" VM ")" ::: "memory");                 \
        __builtin_amdgcn_s_barrier();                                         \
        __builtin_amdgcn_sched_barrier(0);                                    \
        if (ISSUE) STAGE((KS) + 2, PRE);                                      \
        const char* _ab = smem + (CUR) * 24576 + aoff;                        \
        const char* _bb = smem + (CUR) * 24576 + boff;                        \
        short8 _fa[4], _fb[4];                                                \
        _Pragma("unroll")                                                     \
        for (int m = 0; m < 4; ++m) _fa[m] = *(const short8*)(_ab + m * 1024);\
        _Pragma("unroll")                                                     \
        for (int n = 0; n < 4; ++n) _fb[n] = *(const short8*)(_bb + n * 1024);\
        __builtin_amdgcn_s_setprio(1);                                        \
        _Pragma("unroll")                                                     \
        for (int m = 0; m < 4; ++m)                                           \
        _Pragma("unroll")                                                     \
            for (int n = 0; n < 4; ++n)                                       \
                acc[m][n] = __builtin_amdgcn_mfma_f32_16x16x32_bf16(          \
                    _fa[m], _fb[n], acc[m][n], 0, 0, 0);                      \
        __builtin_amdgcn_s_setprio(0);                                        \
    } while (0)

    for (int u = 0; u < 10; ++u) {
        const int ks = u * 3;
        KSTEP(ks + 0, 0, 2, 1, "3");
        KSTEP(ks + 1, 1, 0, 1, "3");
        KSTEP(ks + 2, 2, 1, 1, "3");
    }
    KSTEP(30, 0, 2, 0, "3");
    KSTEP(31, 1, 0, 0, "0");
#undef KSTEP
#undef STAGE
}

// ---------------------------------------------------------------------------
// 128x128 GEMM core (R10, unchanged), used by k_gemm_out.
// ---------------------------------------------------------------------------
DI void gemm_core128(const unsigned short* __restrict__ Ag,
                     const unsigned short* __restrict__ Bg,
                     int m0, int n0, char* smem, f32x4 acc[4][4])
{
    const int t = threadIdx.x, lane = t & 63;
    const int wid = t >> 6, wr = wid >> 1, wc = wid & 1;
    const int kl = lane & 15, hi = lane >> 4;

#pragma unroll
    for (int m = 0; m < 4; ++m)
#pragma unroll
        for (int n = 0; n < 4; ++n)
            acc[m][n] = f32x4{0.f, 0.f, 0.f, 0.f};

    const int ca0 = t,       ra0 = ca0 >> 2, sa0 = ((ca0 & 3) ^ ((ra0 >> 1) & 3)) * 8;
    const int ca1 = t + 256, ra1 = ca1 >> 2, sa1 = ((ca1 & 3) ^ ((ra1 >> 1) & 3)) * 8;
    const unsigned short* pa0 = Ag + (long)(m0 + ra0) * 1024 + sa0;
    const unsigned short* pa1 = Ag + (long)(m0 + ra1) * 1024 + sa1;
    const unsigned short* pb0 = Bg + (long)(n0 + ra0) * 1024 + sa0;
    const unsigned short* pb1 = Bg + (long)(n0 + ra1) * 1024 + sa1;

#define STAGE(TILE, BUF) do {                                          \
        char* _sb = smem + (BUF) * 16384;                              \
        gload_lds16(pa0 + (TILE) * 32, _sb + ca0 * 16);                \
        gload_lds16(pa1 + (TILE) * 32, _sb + ca1 * 16);                \
        gload_lds16(pb0 + (TILE) * 32, _sb + 8192 + ca0 * 16);         \
        gload_lds16(pb1 + (TILE) * 32, _sb + 8192 + ca1 * 16);         \
    } while (0)

    STAGE(0, 0);
    STAGE(1, 1);

    const int swz = ((hi ^ ((kl >> 1) & 3)) << 4);
    const int aoff = (wr * 64 + kl) * 64 + swz;           // + m*1024
    const int boff = 8192 + (wc * 64 + kl) * 64 + swz;    // + n*1024

#define KSTEP(KS, CUR, PRE, ISSUE, VM) do {                                   \
        asm volatile("s_waitcnt vmcnt(" VM ")" ::: "memory");                 \
        __builtin_amdgcn_s_barrier();                                         \
        __builtin_amdgcn_sched_barrier(0);                                    \
        if (ISSUE) STAGE((KS) + 2, PRE);                                      \
        const char* _ab = smem + (CUR) * 16384 + aoff;                        \
        const char* _bb = smem + (CUR) * 16384 + boff;                        \
        short8 _fa[4], _fb[4];                                                \
        _Pragma("unroll")                                                     \
        for (int m = 0; m < 4; ++m) _fa[m] = *(const short8*)(_ab + m * 1024);\
        _Pragma("unroll")                                                     \
        for (int n = 0; n < 4; ++n) _fb[n] = *(const short8*)(_bb + n * 1024);\
        __builtin_amdgcn_s_setprio(1);                                        \
        _Pragma("unroll")                                                     \
        for (int m = 0; m < 4; ++m)                                           \
        _Pragma("unroll")                                                     \
            for (int n = 0; n < 4; ++n)                                       \
                acc[m][n] = __builtin_amdgcn_mfma_f32_16x16x32_bf16(          \
                    _fa[m], _fb[n], acc[m][n], 0, 0, 0);                      \
        __builtin_amdgcn_s_setprio(0);                                        \
    } while (0)

    for (int u = 0; u < 10; ++u) {
        const int ks = u * 3;
        KSTEP(ks + 0, 0, 2, 1, "4");
        KSTEP(ks + 1, 1, 0, 1, "4");
        KSTEP(ks + 2, 2, 1, 1, "4");
    }
    KSTEP(30, 0, 2, 0, "4");
    KSTEP(31, 1, 0, 0, "0");
#undef KSTEP
#undef STAGE
}

// ---------------------------------------------------------------------------
// Kernel 2: fused QKV projection (R10, unchanged). 128x256 tiles, grid
// (64, 12). Q pre-scaled by 0.125*log2e; V written transposed as VT.
// ---------------------------------------------------------------------------
__global__ __launch_bounds__(512, 4) void k_gemm_qkv(
    const unsigned short* __restrict__ xb,
    const unsigned short* __restrict__ wqb, const unsigned short* __restrict__ wkb,
    const unsigned short* __restrict__ wvb,
    unsigned short* __restrict__ Qo, unsigned short* __restrict__ Ko,
    unsigned short* __restrict__ VTo)
{
    extern __shared__ char smem[];
    const int bx = blockIdx.x, by = blockIdx.y;
    const int w = by >> 2, nb = by & 3;
    const unsigned short* Bw = (w == 0) ? wqb : ((w == 1) ? wkb : wvb);
    const float sc = (w == 0) ? 0.18033688011112042f : 1.0f;  // 0.125*log2(e)

    f32x4 acc[4][4];
    gemm_core(xb, Bw, bx * 128, nb * 256, smem, acc);

    const int t = threadIdx.x, lane = t & 63, wid = t >> 6;
    const int wr = wid >> 2, wc = wid & 3, kl = lane & 15, hi = lane >> 4;
    const int h = nb * 4 + wc;       // head (wave-uniform)

    if (w < 2) {
        unsigned short* Ow = (w == 0) ? Qo : Ko;
#pragma unroll
        for (int m = 0; m < 4; ++m)
#pragma unroll
            for (int r = 0; r < 4; ++r) {
                int grow = bx * 128 + wr * 64 + m * 16 + hi * 4 + r;
                int bi = grow >> 12, tt = grow & 4095;
                unsigned short* rowp = Ow + ((long)(bi * 16 + h) * 4096 + tt) * 64;
#pragma unroll
                for (int n = 0; n < 4; ++n)
                    rowp[n * 16 + kl] = f2bf(acc[m][n][r] * sc);
            }
    } else {
#pragma unroll
        for (int m = 0; m < 4; ++m)
#pragma unroll
            for (int r = 0; r < 4; ++r) {
                int grow = bx * 128 + wr * 64 + m * 16 + hi * 4 + r;
                int bi = grow >> 12, tt = grow & 4095;
                unsigned short* hb = VTo + (long)(bi * 16 + h) * 262144;
#pragma unroll
                for (int n = 0; n < 4; ++n) {
                    int d = n * 16 + kl;
                    hb[(long)d * 4096 + tt] = f2bf(acc[m][n][r]);
                }
            }
    }
}

// ---------------------------------------------------------------------------
// Kernel 3: banded sliding-window attention, 4 q-blocks per block.
// Grid 512 = 16 qi-groups x 32 bh (XCD-chunked; single dispatch round at
// 3 blocks/CU). 512 threads = 8 waves; wave w owns HALF of q-block
// 4*qi + (w>>1): rows (w&1)*32 .. +32, processed as two 16-row sub-tiles.
// K/V tiles staged ONCE for all 4 q-blocks (12 tiles vs 4x9): per-qb staging
// and barrier count drop 40% vs the paired (R10) version.
// Q is loaded directly to REGISTERS (read exactly once; no LDS, no swizzle).
// LDS 48KB static: P 16KB + K dbuf 16KB + V dbuf 16KB -> 3 blocks/CU.
// Per-sub compute body is verbatim R10 (proven masks, P roundtrip, exp2).
// ---------------------------------------------------------------------------
__global__ __launch_bounds__(512) void k_attn(
    const unsigned short* __restrict__ Q, const unsigned short* __restrict__ K,
    const unsigned short* __restrict__ VT, unsigned short* __restrict__ AO)
{
    __shared__ unsigned short Ps[8192];            // 8 waves x 2KB P regions
    __shared__ unsigned short Ks[2][4096], Vs[2][4096];
    const int t = threadIdx.x, lane = t & 63, wid = t >> 6;
    const int kl = lane & 15, hi = lane >> 4;
    const int bid = blockIdx.x;
    const int sid = (bid & 7) * 64 + (bid >> 3);   // XCD-chunked (512%8==0)
    const int qi = sid & 15, bh = sid >> 4;
    const int b = bh >> 4, h = bh & 15;
    const int myI = qi * 4 + (wid >> 1);           // this wave's q-block
    const int rbase = (wid >> 1) * 64 + (wid & 1) * 32;  // row base in 256-row grp
    const char* kg = (const char*)(K + (long)bh * 4096 * 64);
    const char* vg = (const char*)(VT + (long)bh * 64 * 4096);

    // Q -> registers: row = qi*256 + rbase + sub*16 + kl; elems kk*32 + hi*8
    short8 aq[2][2];
#pragma unroll
    for (int sub = 0; sub < 2; ++sub)
#pragma unroll
        for (int kk = 0; kk < 2; ++kk) {
            long row = (long)bh * 4096 + qi * 256 + rbase + sub * 16 + kl;
            aq[sub][kk] = *(const short8*)(Q + row * 64 + kk * 32 + hi * 8);
        }

    // K/V staging geometry: 512 chunks (1/thread) per tile
    const int rk = t >> 3, swk = ((t & 7) * 16) ^ ((rk & 7) << 4);
    const char* kgt = kg + rk * 128 + swk;    // + j*8192
    const char* vgt = vg + rk * 8192 + swk;   // + j*128

    const int jlo = (qi * 4 >= 8) ? qi * 4 - 8 : 0;
    const int jhi = qi * 4 + 3;

    gload_lds16(kgt + jlo * 8192, (char*)Ks[0] + t * 16);
    gload_lds16(vgt + jlo * 128,  (char*)Vs[0] + t * 16);
    __syncthreads();

    float lsum[2][4] = {{0.f, 0.f, 0.f, 0.f}, {0.f, 0.f, 0.f, 0.f}};
    f32x4 o[2][4];
#pragma unroll
    for (int sub = 0; sub < 2; ++sub)
#pragma unroll
        for (int nt = 0; nt < 4; ++nt) o[sub][nt] = f32x4{0.f, 0.f, 0.f, 0.f};

    char* pw = (char*)Ps + wid * 2048;         // per-wave P region

    for (int j = jlo; j <= jhi; ++j) {
        const int buf = (j - jlo) & 1;
        if (j < jhi) {                          // deferred prefetch of j+1
            const int nb = buf ^ 1;
            gload_lds16(kgt + (j + 1) * 8192, (char*)Ks[nb] + t * 16);
            gload_lds16(vgt + (j + 1) * 128,  (char*)Vs[nb] + t * 16);
        }

        // wave-uniform activity: window of q-block myI is [myI-8, myI]
        const bool act = (j <= myI) && (j >= myI - 8);
        if (act) {
#pragma unroll
            for (int sub = 0; sub < 2; ++sub) {
                const int qrow = (wid & 1) * 32 + sub * 16 + hi * 4;  // + r
                f32x4 s[4];
#pragma unroll
                for (int nt = 0; nt < 4; ++nt) {
                    s[nt] = f32x4{0.f, 0.f, 0.f, 0.f};
#pragma unroll
                    for (int kk = 0; kk < 2; ++kk)
                        s[nt] = __builtin_amdgcn_mfma_f32_16x16x32_bf16(
                            aq[sub][kk],
                            ldsfrag(Ks[buf], nt * 16 + kl, kk * 64 + hi * 16),
                            s[nt], 0, 0, 0);
                }

                if (j == myI) {               // diagonal: valid iff key <= q
#pragma unroll
                    for (int nt = 0; nt < 4; ++nt) {
                        int key = nt * 16 + kl;
#pragma unroll
                        for (int r = 0; r < 4; ++r)
                            if (key > qrow + r) s[nt][r] = -1e9f;
                    }
                } else if (myI - j == 8) {    // far edge: valid iff key > q
#pragma unroll
                    for (int nt = 0; nt < 4; ++nt) {
                        int key = nt * 16 + kl;
#pragma unroll
                        for (int r = 0; r < 4; ++r)
                            if (key <= qrow + r) s[nt][r] = -1e9f;
                    }
                }

                // p = exp2(s) (log2e pre-folded into Q; masked -> 0)
#pragma unroll
                for (int nt = 0; nt < 4; ++nt)
#pragma unroll
                    for (int r = 0; r < 4; ++r) {
                        float p = exp2f(s[nt][r]);
                        s[nt][r] = p;
                        lsum[sub][r] += p;
                    }

                // P -> per-wave swizzled LDS (C-layout -> A-layout)
#pragma unroll
                for (int nt = 0; nt < 4; ++nt)
#pragma unroll
                    for (int r = 0; r < 4; ++r) {
                        int q = hi * 4 + r;
                        int colb = (nt * 16 + kl) * 2;
                        *(unsigned short*)(pw + q * 128 +
                            (colb ^ ((q & 7) << 4))) = f2bf(s[nt][r]);
                    }

                // O += P V
                short8 pa0 = ldsfrag(pw, kl, hi * 16);
                short8 pa1 = ldsfrag(pw, kl, 64 + hi * 16);
#pragma unroll
                for (int nt = 0; nt < 4; ++nt) {
                    o[sub][nt] = __builtin_amdgcn_mfma_f32_16x16x32_bf16(
                        pa0, ldsfrag(Vs[buf], nt * 16 + kl, hi * 16),
                        o[sub][nt], 0, 0, 0);
                    o[sub][nt] = __builtin_amdgcn_mfma_f32_16x16x32_bf16(
                        pa1, ldsfrag(Vs[buf], nt * 16 + kl, 64 + hi * 16),
                        o[sub][nt], 0, 0, 0);
                }
            }
        }

        __syncthreads();   // implicit vmcnt(0): waits the j+1 prefetch; also
                           // fences buf reads before its overwrite at j+1
    }

    // deferred lsum reduction across the 16 kl lanes (hi preserved)
#pragma unroll
    for (int d = 1; d < 16; d <<= 1)
#pragma unroll
        for (int sub = 0; sub < 2; ++sub)
#pragma unroll
            for (int r = 0; r < 4; ++r)
                lsum[sub][r] += __shfl_xor(lsum[sub][r], d);

#pragma unroll
    for (int sub = 0; sub < 2; ++sub)
#pragma unroll
        for (int r = 0; r < 4; ++r) {
            float inv = 1.0f / lsum[sub][r];
            int tt = qi * 256 + rbase + sub * 16 + hi * 4 + r;
            unsigned short* rowp =
                AO + ((long)(b * 4096 + tt)) * 1024 + h * 64;
#pragma unroll
            for (int nt = 0; nt < 4; ++nt)
                rowp[nt * 16 + kl] = f2bf(o[sub][nt][r] * inv);
        }
}

// ---------------------------------------------------------------------------
// Kernel 4: output projection, 128x128 tiles -> fp32 d_out (R10, unchanged).
// ---------------------------------------------------------------------------
__global__ __launch_bounds__(256, 3) void k_gemm_out(
    const unsigned short* __restrict__ AO, const unsigned short* __restrict__ wob,
    float* __restrict__ out)
{
    extern __shared__ char smem[];
    const int bx = blockIdx.x, nb = blockIdx.y;
    f32x4 acc[4][4];
    gemm_core128(AO, wob, bx * 128, nb * 128, smem, acc);

    const int t = threadIdx.x, lane = t & 63, wid = t >> 6;
    const int wr = wid >> 1, wc = wid & 1, kl = lane & 15, hi = lane >> 4;
#pragma unroll
    for (int m = 0; m < 4; ++m)
#pragma unroll
        for (int r = 0; r < 4; ++r) {
            int grow = bx * 128 + wr * 64 + m * 16 + hi * 4 + r;
            float* rowp = out + (long)grow * 1024 + nb * 128 + wc * 64;
#pragma unroll
            for (int n = 0; n < 4; ++n)
                rowp[n * 16 + kl] = acc[m][n][r];
        }
}

// ---------------------------------------------------------------------------
extern "C" void kernel_launch(void* const* d_in, const int* in_sizes, int n_in,
                              void* d_out, int out_size, void* d_ws, size_t ws_size,
                              hipStream_t stream) {
    const float* x  = (const float*)d_in[0];
    const float* wq = (const float*)d_in[1];
    const float* wk = (const float*)d_in[2];
    const float* wv = (const float*)d_in[3];
    const float* wo = (const float*)d_in[4];

    char* ws = (char*)d_ws;
    const size_t MB = 1024 * 1024;
    unsigned short* xb  = (unsigned short*)(ws);            // 16 MB, reused as AO
    unsigned short* wqb = (unsigned short*)(ws + 16 * MB);  // 2 MB
    unsigned short* wkb = (unsigned short*)(ws + 18 * MB);
    unsigned short* wvb = (unsigned short*)(ws + 20 * MB);
    unsigned short* wob = (unsigned short*)(ws + 22 * MB);
    unsigned short* Qp  = (unsigned short*)(ws + 24 * MB);  // 16 MB each
    unsigned short* Kp  = (unsigned short*)(ws + 40 * MB);
    unsigned short* VTp = (unsigned short*)(ws + 56 * MB);  // end 72 MB
    unsigned short* AOp = xb;  // x no longer needed after QKV GEMM

    hipFuncSetAttribute((const void*)k_gemm_qkv,
                        hipFuncAttributeMaxDynamicSharedMemorySize, 73728);
    hipFuncSetAttribute((const void*)k_gemm_out,
                        hipFuncAttributeMaxDynamicSharedMemorySize, 49152);

    dim3 blk(256);
    k_cvt<<<6144, blk, 0, stream>>>(x, wq, wk, wv, wo,
                                    xb, wqb, wkb, wvb, wob);
    k_gemm_qkv<<<dim3(64, 12), 512, 73728, stream>>>(xb, wqb, wkb, wvb,
                                                     Qp, Kp, VTp);
    k_attn<<<512, 512, 0, stream>>>(Qp, Kp, VTp, AOp);
    k_gemm_out<<<dim3(64, 8), 256, 49152, stream>>>(AOp, wob, (float*)d_out);
}

// Round 15
// 135.555 us; speedup vs baseline: 1.1280x; 1.1280x over previous
//
#include <hip/hip_runtime.h>

#define DI static __device__ __forceinline__

typedef __attribute__((ext_vector_type(8))) short short8;  // 8 bf16 in 4 VGPRs
typedef __attribute__((ext_vector_type(4))) float f32x4;

// fp32 -> bf16 round-to-nearest-even
DI unsigned short f2bf(float f) {
    union { float f; unsigned int u; } v; v.f = f;
    unsigned int r = v.u + 0x7FFFu + ((v.u >> 16) & 1u);
    return (unsigned short)(r >> 16);
}

// pack two fp32 -> u32 of 2 bf16 (RNE)
DI unsigned int f2bf2(float lo, float hi) {
    return (unsigned int)f2bf(lo) | ((unsigned int)f2bf(hi) << 16);
}

// async global->LDS, 16B per lane. LDS dest must be wave-uniform base + lane*16.
DI void gload_lds16(const void* g, void* l) {
    __builtin_amdgcn_global_load_lds(
        (const __attribute__((address_space(1))) void*)g,
        (__attribute__((address_space(3))) void*)l, 16, 0, 0);
}

// swizzled LDS fragment read for 128B-row tiles (attention)
DI short8 ldsfrag(const void* base, int row, int bytecol) {
    return *(const short8*)((const char*)base + row * 128 + (bytecol ^ ((row & 7) << 4)));
}

// ---------------------------------------------------------------------------
// Kernel 1: fp32 -> bf16 conversion, flat 1D grid, 8 elems/thread, 16B store
// ---------------------------------------------------------------------------
__global__ __launch_bounds__(256) void k_cvt(
    const float* __restrict__ x, const float* __restrict__ wq,
    const float* __restrict__ wk, const float* __restrict__ wv,
    const float* __restrict__ wo,
    unsigned short* __restrict__ xb, unsigned short* __restrict__ wqb,
    unsigned short* __restrict__ wkb, unsigned short* __restrict__ wvb,
    unsigned short* __restrict__ wob)
{
    int idx = (blockIdx.x * 256 + threadIdx.x) * 8;   // < 12582912
    const float* src; unsigned short* dst; int off;
    if (idx < 8388608) {
        src = x; dst = xb; off = idx;
    } else {
        int rel = idx - 8388608;
        int sel = rel >> 20;
        off = rel & 1048575;
        switch (sel) {
            case 0:  src = wq; dst = wqb; break;
            case 1:  src = wk; dst = wkb; break;
            case 2:  src = wv; dst = wvb; break;
            default: src = wo; dst = wob; break;
        }
    }
    float4 v0 = *(const float4*)(src + off);
    float4 v1 = *(const float4*)(src + off + 4);
    uint4 o;
    o.x = f2bf2(v0.x, v0.y);
    o.y = f2bf2(v0.z, v0.w);
    o.z = f2bf2(v1.x, v1.y);
    o.w = f2bf2(v1.z, v1.w);
    *(uint4*)(dst + off) = o;
}

// ---------------------------------------------------------------------------
// 128x256 GEMM core (R6/R9/R10-proven, 888 TF, 0 conflicts): BK=32, K=1024,
// 8 waves (2M x 4N), 3 LDS bufs x 24KB = 72KB, counted-vmcnt(3) pipeline.
// ---------------------------------------------------------------------------
DI void gemm_core(const unsigned short* __restrict__ Ag,
                  const unsigned short* __restrict__ Bg,
                  int m0, int n0, char* smem, f32x4 acc[4][4])
{
    const int t = threadIdx.x, lane = t & 63;
    const int wid = t >> 6, wr = wid >> 2, wc = wid & 3;
    const int kl = lane & 15, hi = lane >> 4;

#pragma unroll
    for (int m = 0; m < 4; ++m)
#pragma unroll
        for (int n = 0; n < 4; ++n)
            acc[m][n] = f32x4{0.f, 0.f, 0.f, 0.f};

    const int ca  = t,       ra  = ca  >> 2, sa  = ((ca  & 3) ^ ((ra  >> 1) & 3)) * 8;
    const int cb0 = t,       rb0 = cb0 >> 2, sb0 = ((cb0 & 3) ^ ((rb0 >> 1) & 3)) * 8;
    const int cb1 = t + 512, rb1 = cb1 >> 2, sb1 = ((cb1 & 3) ^ ((rb1 >> 1) & 3)) * 8;
    const unsigned short* pa  = Ag + (long)(m0 + ra)  * 1024 + sa;
    const unsigned short* pb0 = Bg + (long)(n0 + rb0) * 1024 + sb0;
    const unsigned short* pb1 = Bg + (long)(n0 + rb1) * 1024 + sb1;

#define STAGE(TILE, BUF) do {                                          \
        char* _sb = smem + (BUF) * 24576;                              \
        gload_lds16(pa  + (TILE) * 32, _sb + ca * 16);                 \
        gload_lds16(pb0 + (TILE) * 32, _sb + 8192 + cb0 * 16);         \
        gload_lds16(pb1 + (TILE) * 32, _sb + 8192 + cb1 * 16);         \
    } while (0)

    STAGE(0, 0);
    STAGE(1, 1);

    const int swz = ((hi ^ ((kl >> 1) & 3)) << 4);
    const int aoff = (wr * 64 + kl) * 64 + swz;           // + m*1024
    const int boff = 8192 + (wc * 64 + kl) * 64 + swz;    // + n*1024

#define KSTEP(KS, CUR, PRE, ISSUE, VM) do {                                   \
        asm volatile("s_waitcnt vmcnt(" VM ")" ::: "memory");                 \
        __builtin_amdgcn_s_barrier();                                         \
        __builtin_amdgcn_sched_barrier(0);                                    \
        if (ISSUE) STAGE((KS) + 2, PRE);                                      \
        const char* _ab = smem + (CUR) * 24576 + aoff;                        \
        const char* _bb = smem + (CUR) * 24576 + boff;                        \
        short8 _fa[4], _fb[4];                                                \
        _Pragma("unroll")                                                     \
        for (int m = 0; m < 4; ++m) _fa[m] = *(const short8*)(_ab + m * 1024);\
        _Pragma("unroll")                                                     \
        for (int n = 0; n < 4; ++n) _fb[n] = *(const short8*)(_bb + n * 1024);\
        __builtin_amdgcn_s_setprio(1);                                        \
        _Pragma("unroll")                                                     \
        for (int m = 0; m < 4; ++m)                                           \
        _Pragma("unroll")                                                     \
            for (int n = 0; n < 4; ++n)                                       \
                acc[m][n] = __builtin_amdgcn_mfma_f32_16x16x32_bf16(          \
                    _fa[m], _fb[n], acc[m][n], 0, 0, 0);                      \
        __builtin_amdgcn_s_setprio(0);                                        \
    } while (0)

    for (int u = 0; u < 10; ++u) {
        const int ks = u * 3;
        KSTEP(ks + 0, 0, 2, 1, "3");
        KSTEP(ks + 1, 1, 0, 1, "3");
        KSTEP(ks + 2, 2, 1, 1, "3");
    }
    KSTEP(30, 0, 2, 0, "3");
    KSTEP(31, 1, 0, 0, "0");
#undef KSTEP
#undef STAGE
}

// ---------------------------------------------------------------------------
// 128x128 GEMM core (R10, unchanged), used by k_gemm_out.
// ---------------------------------------------------------------------------
DI void gemm_core128(const unsigned short* __restrict__ Ag,
                     const unsigned short* __restrict__ Bg,
                     int m0, int n0, char* smem, f32x4 acc[4][4])
{
    const int t = threadIdx.x, lane = t & 63;
    const int wid = t >> 6, wr = wid >> 1, wc = wid & 1;
    const int kl = lane & 15, hi = lane >> 4;

#pragma unroll
    for (int m = 0; m < 4; ++m)
#pragma unroll
        for (int n = 0; n < 4; ++n)
            acc[m][n] = f32x4{0.f, 0.f, 0.f, 0.f};

    const int ca0 = t,       ra0 = ca0 >> 2, sa0 = ((ca0 & 3) ^ ((ra0 >> 1) & 3)) * 8;
    const int ca1 = t + 256, ra1 = ca1 >> 2, sa1 = ((ca1 & 3) ^ ((ra1 >> 1) & 3)) * 8;
    const unsigned short* pa0 = Ag + (long)(m0 + ra0) * 1024 + sa0;
    const unsigned short* pa1 = Ag + (long)(m0 + ra1) * 1024 + sa1;
    const unsigned short* pb0 = Bg + (long)(n0 + ra0) * 1024 + sa0;
    const unsigned short* pb1 = Bg + (long)(n0 + ra1) * 1024 + sa1;

#define STAGE(TILE, BUF) do {                                          \
        char* _sb = smem + (BUF) * 16384;                              \
        gload_lds16(pa0 + (TILE) * 32, _sb + ca0 * 16);                \
        gload_lds16(pa1 + (TILE) * 32, _sb + ca1 * 16);                \
        gload_lds16(pb0 + (TILE) * 32, _sb + 8192 + ca0 * 16);         \
        gload_lds16(pb1 + (TILE) * 32, _sb + 8192 + ca1 * 16);         \
    } while (0)

    STAGE(0, 0);
    STAGE(1, 1);

    const int swz = ((hi ^ ((kl >> 1) & 3)) << 4);
    const int aoff = (wr * 64 + kl) * 64 + swz;           // + m*1024
    const int boff = 8192 + (wc * 64 + kl) * 64 + swz;    // + n*1024

#define KSTEP(KS, CUR, PRE, ISSUE, VM) do {                                   \
        asm volatile("s_waitcnt vmcnt(" VM ")" ::: "memory");                 \
        __builtin_amdgcn_s_barrier();                                         \
        __builtin_amdgcn_sched_barrier(0);                                    \
        if (ISSUE) STAGE((KS) + 2, PRE);                                      \
        const char* _ab = smem + (CUR) * 16384 + aoff;                        \
        const char* _bb = smem + (CUR) * 16384 + boff;                        \
        short8 _fa[4], _fb[4];                                                \
        _Pragma("unroll")                                                     \
        for (int m = 0; m < 4; ++m) _fa[m] = *(const short8*)(_ab + m * 1024);\
        _Pragma("unroll")                                                     \
        for (int n = 0; n < 4; ++n) _fb[n] = *(const short8*)(_bb + n * 1024);\
        __builtin_amdgcn_s_setprio(1);                                        \
        _Pragma("unroll")                                                     \
        for (int m = 0; m < 4; ++m)                                           \
        _Pragma("unroll")                                                     \
            for (int n = 0; n < 4; ++n)                                       \
                acc[m][n] = __builtin_amdgcn_mfma_f32_16x16x32_bf16(          \
                    _fa[m], _fb[n], acc[m][n], 0, 0, 0);                      \
        __builtin_amdgcn_s_setprio(0);                                        \
    } while (0)

    for (int u = 0; u < 10; ++u) {
        const int ks = u * 3;
        KSTEP(ks + 0, 0, 2, 1, "4");
        KSTEP(ks + 1, 1, 0, 1, "4");
        KSTEP(ks + 2, 2, 1, 1, "4");
    }
    KSTEP(30, 0, 2, 0, "4");
    KSTEP(31, 1, 0, 0, "0");
#undef KSTEP
#undef STAGE
}

// ---------------------------------------------------------------------------
// Kernel 2: fused QKV projection (R10, unchanged). 128x256 tiles, grid
// (64, 12). Q pre-scaled by 0.125*log2e; V written transposed as VT.
// ---------------------------------------------------------------------------
__global__ __launch_bounds__(512, 4) void k_gemm_qkv(
    const unsigned short* __restrict__ xb,
    const unsigned short* __restrict__ wqb, const unsigned short* __restrict__ wkb,
    const unsigned short* __restrict__ wvb,
    unsigned short* __restrict__ Qo, unsigned short* __restrict__ Ko,
    unsigned short* __restrict__ VTo)
{
    extern __shared__ char smem[];
    const int bx = blockIdx.x, by = blockIdx.y;
    const int w = by >> 2, nb = by & 3;
    const unsigned short* Bw = (w == 0) ? wqb : ((w == 1) ? wkb : wvb);
    const float sc = (w == 0) ? 0.18033688011112042f : 1.0f;  // 0.125*log2(e)

    f32x4 acc[4][4];
    gemm_core(xb, Bw, bx * 128, nb * 256, smem, acc);

    const int t = threadIdx.x, lane = t & 63, wid = t >> 6;
    const int wr = wid >> 2, wc = wid & 3, kl = lane & 15, hi = lane >> 4;
    const int h = nb * 4 + wc;       // head (wave-uniform)

    if (w < 2) {
        unsigned short* Ow = (w == 0) ? Qo : Ko;
#pragma unroll
        for (int m = 0; m < 4; ++m)
#pragma unroll
            for (int r = 0; r < 4; ++r) {
                int grow = bx * 128 + wr * 64 + m * 16 + hi * 4 + r;
                int bi = grow >> 12, tt = grow & 4095;
                unsigned short* rowp = Ow + ((long)(bi * 16 + h) * 4096 + tt) * 64;
#pragma unroll
                for (int n = 0; n < 4; ++n)
                    rowp[n * 16 + kl] = f2bf(acc[m][n][r] * sc);
            }
    } else {
#pragma unroll
        for (int m = 0; m < 4; ++m)
#pragma unroll
            for (int r = 0; r < 4; ++r) {
                int grow = bx * 128 + wr * 64 + m * 16 + hi * 4 + r;
                int bi = grow >> 12, tt = grow & 4095;
                unsigned short* hb = VTo + (long)(bi * 16 + h) * 262144;
#pragma unroll
                for (int n = 0; n < 4; ++n) {
                    int d = n * 16 + kl;
                    hb[(long)d * 4096 + tt] = f2bf(acc[m][n][r]);
                }
            }
    }
}

// ---------------------------------------------------------------------------
// Kernel 3: banded sliding-window attention, PAIRED q-blocks (R13 best
// version: R10 structure, 48KB static LDS -> 3 blocks/CU).
// 512 threads = 8 waves: waves 0-3 own q-block iA=2*qi, waves 4-7 own iB.
// K/V double-buffered, deferred staging; no-max softmax via exp2.
// ---------------------------------------------------------------------------
__global__ __launch_bounds__(512) void k_attn(
    const unsigned short* __restrict__ Q, const unsigned short* __restrict__ K,
    const unsigned short* __restrict__ VT, unsigned short* __restrict__ AO)
{
    __shared__ unsigned short Qs[8192];            // 128 q-rows; reused as P
    __shared__ unsigned short Ks[2][4096], Vs[2][4096];
    const int t = threadIdx.x, lane = t & 63, wid = t >> 6;
    const int kl = lane & 15, hi = lane >> 4;
    const int bid = blockIdx.x;
    const int sid = (bid & 7) * 128 + (bid >> 3);  // XCD-chunked (1024%8==0)
    const int qi = sid & 31, bh = sid >> 5;
    const int b = bh >> 4, h = bh & 15;
    const int iA = qi * 2, iB = qi * 2 + 1;
    const int myI = (wid < 4) ? iA : iB;           // this wave's q-block
    const char* qg = (const char*)(Q + ((long)bh * 4096 + qi * 128) * 64);
    const char* kg = (const char*)(K + (long)bh * 4096 * 64);
    const char* vg = (const char*)(VT + (long)bh * 64 * 4096);

    const int cq0 = t, cq1 = t + 512;
    const int rq0 = cq0 >> 3, sq0 = ((cq0 & 7) * 16) ^ ((rq0 & 7) << 4);
    const int rq1 = cq1 >> 3, sq1 = ((cq1 & 7) * 16) ^ ((rq1 & 7) << 4);
    const int rk = t >> 3, swk = ((t & 7) * 16) ^ ((rk & 7) << 4);
    const char* kgt = kg + rk * 128 + swk;    // + j*8192
    const char* vgt = vg + rk * 8192 + swk;   // + j*128

    const int jlo = (iA >= 8) ? iA - 8 : 0;
    const int jhi = iB;

    gload_lds16(qg + rq0 * 128 + sq0, (char*)Qs + cq0 * 16);
    gload_lds16(qg + rq1 * 128 + sq1, (char*)Qs + cq1 * 16);
    gload_lds16(kgt + jlo * 8192, (char*)Ks[0] + t * 16);
    gload_lds16(vgt + jlo * 128,  (char*)Vs[0] + t * 16);
    __syncthreads();

    short8 aq[2];
    aq[0] = ldsfrag(Qs, wid * 16 + kl, hi * 16);
    aq[1] = ldsfrag(Qs, wid * 16 + kl, 64 + hi * 16);

    float lsum[4] = {0.f, 0.f, 0.f, 0.f};
    f32x4 o[4];
#pragma unroll
    for (int nt = 0; nt < 4; ++nt) o[nt] = f32x4{0.f, 0.f, 0.f, 0.f};

    const int qrow = (wid & 3) * 16 + hi * 4;  // + r (row within own q-block)
    char* pw = (char*)Qs + wid * 2048;         // per-wave P region (own Q rows)

    for (int j = jlo; j <= jhi; ++j) {
        const int buf = (j - jlo) & 1;
        if (j < jhi) {                          // deferred prefetch of j+1
            const int nb = buf ^ 1;
            gload_lds16(kgt + (j + 1) * 8192, (char*)Ks[nb] + t * 16);
            gload_lds16(vgt + (j + 1) * 128,  (char*)Vs[nb] + t * 16);
        }

        const bool act = (wid < 4) ? (j <= iA) : (j >= iB - 8);
        if (act) {
            f32x4 s[4];
#pragma unroll
            for (int nt = 0; nt < 4; ++nt) {
                s[nt] = f32x4{0.f, 0.f, 0.f, 0.f};
#pragma unroll
                for (int kk = 0; kk < 2; ++kk)
                    s[nt] = __builtin_amdgcn_mfma_f32_16x16x32_bf16(
                        aq[kk], ldsfrag(Ks[buf], nt * 16 + kl, kk * 64 + hi * 16),
                        s[nt], 0, 0, 0);
            }

            if (j == myI) {               // diagonal: valid iff key <= q
#pragma unroll
                for (int nt = 0; nt < 4; ++nt) {
                    int key = nt * 16 + kl;
#pragma unroll
                    for (int r = 0; r < 4; ++r)
                        if (key > qrow + r) s[nt][r] = -1e9f;
                }
            } else if (myI - j == 8) {    // far edge: valid iff key > q
#pragma unroll
                for (int nt = 0; nt < 4; ++nt) {
                    int key = nt * 16 + kl;
#pragma unroll
                    for (int r = 0; r < 4; ++r)
                        if (key <= qrow + r) s[nt][r] = -1e9f;
                }
            }

#pragma unroll
            for (int nt = 0; nt < 4; ++nt)
#pragma unroll
                for (int r = 0; r < 4; ++r) {
                    float p = exp2f(s[nt][r]);
                    s[nt][r] = p;
                    lsum[r] += p;
                }

#pragma unroll
            for (int nt = 0; nt < 4; ++nt)
#pragma unroll
                for (int r = 0; r < 4; ++r) {
                    int q = hi * 4 + r;
                    int colb = (nt * 16 + kl) * 2;
                    *(unsigned short*)(pw + q * 128 + (colb ^ ((q & 7) << 4))) =
                        f2bf(s[nt][r]);
                }

            short8 pa0 = ldsfrag(pw, kl, hi * 16);
            short8 pa1 = ldsfrag(pw, kl, 64 + hi * 16);
#pragma unroll
            for (int nt = 0; nt < 4; ++nt) {
                o[nt] = __builtin_amdgcn_mfma_f32_16x16x32_bf16(
                    pa0, ldsfrag(Vs[buf], nt * 16 + kl, hi * 16), o[nt], 0, 0, 0);
                o[nt] = __builtin_amdgcn_mfma_f32_16x16x32_bf16(
                    pa1, ldsfrag(Vs[buf], nt * 16 + kl, 64 + hi * 16), o[nt], 0, 0, 0);
            }
        }

        __syncthreads();
    }

#pragma unroll
    for (int d = 1; d < 16; d <<= 1)
#pragma unroll
        for (int r = 0; r < 4; ++r) lsum[r] += __shfl_xor(lsum[r], d);

    float inv[4];
#pragma unroll
    for (int r = 0; r < 4; ++r) inv[r] = 1.0f / lsum[r];
#pragma unroll
    for (int r = 0; r < 4; ++r) {
        int tt = qi * 128 + wid * 16 + hi * 4 + r;
        unsigned short* rowp = AO + ((long)(b * 4096 + tt)) * 1024 + h * 64;
#pragma unroll
        for (int nt = 0; nt < 4; ++nt)
            rowp[nt * 16 + kl] = f2bf(o[nt][r] * inv[r]);
    }
}

// ---------------------------------------------------------------------------
// Kernel 4: output projection, 128x128 tiles -> fp32 d_out (R10, unchanged).
// ---------------------------------------------------------------------------
__global__ __launch_bounds__(256, 3) void k_gemm_out(
    const unsigned short* __restrict__ AO, const unsigned short* __restrict__ wob,
    float* __restrict__ out)
{
    extern __shared__ char smem[];
    const int bx = blockIdx.x, nb = blockIdx.y;
    f32x4 acc[4][4];
    gemm_core128(AO, wob, bx * 128, nb * 128, smem, acc);

    const int t = threadIdx.x, lane = t & 63, wid = t >> 6;
    const int wr = wid >> 1, wc = wid & 1, kl = lane & 15, hi = lane >> 4;
#pragma unroll
    for (int m = 0; m < 4; ++m)
#pragma unroll
        for (int r = 0; r < 4; ++r) {
            int grow = bx * 128 + wr * 64 + m * 16 + hi * 4 + r;
            float* rowp = out + (long)grow * 1024 + nb * 128 + wc * 64;
#pragma unroll
            for (int n = 0; n < 4; ++n)
                rowp[n * 16 + kl] = acc[m][n][r];
        }
}

// ---------------------------------------------------------------------------
extern "C" void kernel_launch(void* const* d_in, const int* in_sizes, int n_in,
                              void* d_out, int out_size, void* d_ws, size_t ws_size,
                              hipStream_t stream) {
    const float* x  = (const float*)d_in[0];
    const float* wq = (const float*)d_in[1];
    const float* wk = (const float*)d_in[2];
    const float* wv = (const float*)d_in[3];
    const float* wo = (const float*)d_in[4];

    char* ws = (char*)d_ws;
    const size_t MB = 1024 * 1024;
    unsigned short* xb  = (unsigned short*)(ws);            // 16 MB, reused as AO
    unsigned short* wqb = (unsigned short*)(ws + 16 * MB);  // 2 MB
    unsigned short* wkb = (unsigned short*)(ws + 18 * MB);
    unsigned short* wvb = (unsigned short*)(ws + 20 * MB);
    unsigned short* wob = (unsigned short*)(ws + 22 * MB);
    unsigned short* Qp  = (unsigned short*)(ws + 24 * MB);  // 16 MB each
    unsigned short* Kp  = (unsigned short*)(ws + 40 * MB);
    unsigned short* VTp = (unsigned short*)(ws + 56 * MB);  // end 72 MB
    unsigned short* AOp = xb;  // x no longer needed after QKV GEMM

    hipFuncSetAttribute((const void*)k_gemm_qkv,
                        hipFuncAttributeMaxDynamicSharedMemorySize, 73728);
    hipFuncSetAttribute((const void*)k_gemm_out,
                        hipFuncAttributeMaxDynamicSharedMemorySize, 49152);

    dim3 blk(256);
    k_cvt<<<6144, blk, 0, stream>>>(x, wq, wk, wv, wo,
                                    xb, wqb, wkb, wvb, wob);
    k_gemm_qkv<<<dim3(64, 12), 512, 73728, stream>>>(xb, wqb, wkb, wvb,
                                                     Qp, Kp, VTp);
    k_attn<<<1024, 512, 0, stream>>>(Qp, Kp, VTp, AOp);
    k_gemm_out<<<dim3(64, 8), 256, 49152, stream>>>(AOp, wob, (float*)d_out);
}